// Round 1
// baseline (915.844 us; speedup 1.0000x reference)
//
#include <hip/hip_runtime.h>
#include <cstdint>
#include <cstddef>

constexpr int HH = 1024;   // hidden dim (fixed for this problem)
constexpr int II = 1024;   // intermediate dim
constexpr int TT = 8;      // token tile per block
constexpr int KMAX = 2;    // top-k (k=2 in setup)
constexpr int EMAX = 8;

constexpr float FALPHA = 1.702f;
constexpr float FLIMIT = 7.0f;

// fp4 e2m1 magnitude*2 as a small int, sign applied: returns LUT[c]*2
__device__ __forceinline__ float fp4k(int c) {
  int mag = c & 7;
  int e = mag >> 1, m = mag & 1;
  int k = (e == 0) ? mag : ((2 + m) << (e - 1));
  return (float)((c & 8) ? -k : k);
}
// 0.5 * 2^(s-127) = 2^(s-128); s in [121,130] so s-1 in [120,129] is a valid biased exp
__device__ __forceinline__ float sc_half(int s) {
  return __uint_as_float((unsigned)(s - 1) << 23);
}
__device__ __forceinline__ void decode8(int4 b, float sc, float w[8]) {
  w[0] = fp4k(b.x & 15) * sc; w[1] = fp4k((b.x >> 4) & 15) * sc;
  w[2] = fp4k(b.y & 15) * sc; w[3] = fp4k((b.y >> 4) & 15) * sc;
  w[4] = fp4k(b.z & 15) * sc; w[5] = fp4k((b.z >> 4) & 15) * sc;
  w[6] = fp4k(b.w & 15) * sc; w[7] = fp4k((b.w >> 4) & 15) * sc;
}

__global__ void routing_kernel(const float* __restrict__ logits, const int* __restrict__ dk,
                               int T, int E, float* __restrict__ route,
                               int* __restrict__ tidx, float* __restrict__ tw) {
  int t = blockIdx.x * blockDim.x + threadIdx.x;
  if (t >= T) return;
  int kk = *dk; if (kk > KMAX) kk = KMAX; if (kk < 1) kk = 1;
  int EE = E > EMAX ? EMAX : E;
  float v[EMAX]; bool used[EMAX];
  for (int e = 0; e < EE; ++e) { v[e] = logits[t * E + e]; used[e] = false; route[t * E + e] = 0.f; }
  float tv[KMAX]; int ti[KMAX];
  for (int j = 0; j < kk; ++j) {
    float best = -3.4e38f; int bi = 0;
    for (int e = 0; e < EE; ++e) if (!used[e] && v[e] > best) { best = v[e]; bi = e; }
    used[bi] = true; tv[j] = best; ti[j] = bi;
  }
  float mx = tv[0], ssum = 0.f;
  float wj[KMAX];
  for (int j = 0; j < kk; ++j) { wj[j] = __expf(tv[j] - mx); ssum += wj[j]; }
  for (int j = 0; j < kk; ++j) {
    float wv = wj[j] / ssum;
    route[t * E + ti[j]] = wv;
    tidx[t * kk + j] = ti[j];
    tw[t * kk + j] = wv;
  }
}

__global__ void build_lists(const int* __restrict__ tidx, const int* __restrict__ dk,
                            int T, int* __restrict__ lists, int* __restrict__ counts) {
  int e = blockIdx.x;
  int lane = threadIdx.x;  // 64 threads = 1 wave
  int kk = *dk; if (kk > KMAX) kk = KMAX; if (kk < 1) kk = 1;
  int cnt = 0;
  for (int base = 0; base < T; base += 64) {
    int t = base + lane;
    int j = -1;
    if (t < T) {
      for (int q = 0; q < kk; ++q) if (tidx[t * kk + q] == e) j = q;
    }
    unsigned long long m = __ballot(j >= 0);
    if (j >= 0) {
      int pre = __popcll(m & ((1ull << lane) - 1ull));
      lists[e * T + cnt + pre] = (t << 3) | j;
    }
    cnt += __popcll(m);
  }
  if (lane == 0) counts[e] = cnt;
}

__global__ __launch_bounds__(256) void gate_up_act(
    const float* __restrict__ hs,
    const int* __restrict__ gblk, const int* __restrict__ gscl, const float* __restrict__ gbias,
    const int* __restrict__ ublk, const int* __restrict__ uscl, const float* __restrict__ ubias,
    const int* __restrict__ lists, const int* __restrict__ counts,
    const float* __restrict__ tw, const int* __restrict__ dk,
    float* __restrict__ act, int T, int tilesPerE)
{
  int e = blockIdx.x / tilesPerE, tile = blockIdx.x % tilesPerE;
  int n = counts[e] - tile * TT;
  if (n <= 0) return;
  if (n > TT) n = TT;
  int kk = *dk; if (kk > KMAX) kk = KMAX; if (kk < 1) kk = 1;

  __shared__ float4 hid[TT][HH / 4];   // 32 KB
  __shared__ int s_entry[TT];

  if (threadIdx.x < TT) {
    int idx = tile * TT + (threadIdx.x < n ? threadIdx.x : 0);
    s_entry[threadIdx.x] = lists[e * T + idx];
  }
  __syncthreads();
  #pragma unroll
  for (int tok = 0; tok < TT; ++tok) {
    int t = s_entry[tok] >> 3;
    hid[tok][threadIdx.x] = ((const float4*)(hs + (size_t)t * HH))[threadIdx.x];
  }
  __syncthreads();

  int i0 = blockIdx.y * 256 + threadIdx.x;   // gridDim.y = II/512, rows i0 and i0+512
  int i1 = i0 + II / 2;

  const int4* gp0 = (const int4*)(gblk + ((size_t)e * II + i0) * (HH / 2));
  const int4* gp1 = (const int4*)(gblk + ((size_t)e * II + i1) * (HH / 2));
  const int4* up0 = (const int4*)(ublk + ((size_t)e * II + i0) * (HH / 2));
  const int4* up1 = (const int4*)(ublk + ((size_t)e * II + i1) * (HH / 2));
  const int* gs0 = gscl + ((size_t)e * II + i0) * (HH / 32);
  const int* gs1 = gscl + ((size_t)e * II + i1) * (HH / 32);
  const int* us0 = uscl + ((size_t)e * II + i0) * (HH / 32);
  const int* us1 = uscl + ((size_t)e * II + i1) * (HH / 32);

  float ag0[TT] = {}, au0[TT] = {}, ag1[TT] = {}, au1[TT] = {};

  for (int hb = 0; hb < HH / 32; ++hb) {
    float scg0 = sc_half(gs0[hb]), scu0 = sc_half(us0[hb]);
    float scg1 = sc_half(gs1[hb]), scu1 = sc_half(us1[hb]);
    #pragma unroll
    for (int c = 0; c < 4; ++c) {
      float wg0[8], wu0[8], wg1[8], wu1[8];
      decode8(gp0[hb * 4 + c], scg0, wg0);
      decode8(up0[hb * 4 + c], scu0, wu0);
      decode8(gp1[hb * 4 + c], scg1, wg1);
      decode8(up1[hb * 4 + c], scu1, wu1);
      int h4 = hb * 8 + c * 2;
      #pragma unroll
      for (int tok = 0; tok < TT; ++tok) {
        float4 a = hid[tok][h4], b = hid[tok][h4 + 1];
        ag0[tok] += wg0[0]*a.x + wg0[1]*a.y + wg0[2]*a.z + wg0[3]*a.w
                  + wg0[4]*b.x + wg0[5]*b.y + wg0[6]*b.z + wg0[7]*b.w;
        au0[tok] += wu0[0]*a.x + wu0[1]*a.y + wu0[2]*a.z + wu0[3]*a.w
                  + wu0[4]*b.x + wu0[5]*b.y + wu0[6]*b.z + wu0[7]*b.w;
        ag1[tok] += wg1[0]*a.x + wg1[1]*a.y + wg1[2]*a.z + wg1[3]*a.w
                  + wg1[4]*b.x + wg1[5]*b.y + wg1[6]*b.z + wg1[7]*b.w;
        au1[tok] += wu1[0]*a.x + wu1[1]*a.y + wu1[2]*a.z + wu1[3]*a.w
                  + wu1[4]*b.x + wu1[5]*b.y + wu1[6]*b.z + wu1[7]*b.w;
      }
    }
  }

  float gb0 = gbias[e * II + i0], ub0 = ubias[e * II + i0];
  float gb1 = gbias[e * II + i1], ub1 = ubias[e * II + i1];
  #pragma unroll
  for (int tok = 0; tok < TT; ++tok) {
    if (tok < n) {
      int entry = s_entry[tok]; int t = entry >> 3, j = entry & 7;
      float wv = tw[t * kk + j];
      size_t slot = (size_t)t * kk + j;
      {
        float g = fminf(ag0[tok] + gb0, FLIMIT);
        float u = fminf(fmaxf(au0[tok] + ub0, -FLIMIT), FLIMIT);
        float glu = g / (1.f + __expf(-FALPHA * g));
        act[slot * II + i0] = (u + 1.f) * glu * wv;
      }
      {
        float g = fminf(ag1[tok] + gb1, FLIMIT);
        float u = fminf(fmaxf(au1[tok] + ub1, -FLIMIT), FLIMIT);
        float glu = g / (1.f + __expf(-FALPHA * g));
        act[slot * II + i1] = (u + 1.f) * glu * wv;
      }
    }
  }
}

__global__ __launch_bounds__(256) void down_proj(
    const float* __restrict__ act,
    const int* __restrict__ dblk, const int* __restrict__ dscl,
    const int* __restrict__ lists, const int* __restrict__ counts,
    const int* __restrict__ dk,
    float* __restrict__ partial, int T, int tilesPerE)
{
  int e = blockIdx.x / tilesPerE, tile = blockIdx.x % tilesPerE;
  int n = counts[e] - tile * TT;
  if (n <= 0) return;
  if (n > TT) n = TT;
  int kk = *dk; if (kk > KMAX) kk = KMAX; if (kk < 1) kk = 1;

  __shared__ float4 av[TT][II / 4];    // 32 KB
  __shared__ int s_entry[TT];
  if (threadIdx.x < TT) {
    int idx = tile * TT + (threadIdx.x < n ? threadIdx.x : 0);
    s_entry[threadIdx.x] = lists[e * T + idx];
  }
  __syncthreads();
  #pragma unroll
  for (int tok = 0; tok < TT; ++tok) {
    int entry = s_entry[tok]; int t = entry >> 3, j = entry & 7;
    av[tok][threadIdx.x] = ((const float4*)(act + ((size_t)t * kk + j) * II))[threadIdx.x];
  }
  __syncthreads();

  int h0 = blockIdx.y * 256 + threadIdx.x;   // gridDim.y = HH/512
  int h1 = h0 + HH / 2;
  const int4* dp0 = (const int4*)(dblk + ((size_t)e * HH + h0) * (II / 2));
  const int4* dp1 = (const int4*)(dblk + ((size_t)e * HH + h1) * (II / 2));
  const int* ds0 = dscl + ((size_t)e * HH + h0) * (II / 32);
  const int* ds1 = dscl + ((size_t)e * HH + h1) * (II / 32);

  float a0[TT] = {}, a1[TT] = {};
  for (int ib = 0; ib < II / 32; ++ib) {
    float sc0 = sc_half(ds0[ib]), sc1 = sc_half(ds1[ib]);
    #pragma unroll
    for (int c = 0; c < 4; ++c) {
      float w0[8], w1[8];
      decode8(dp0[ib * 4 + c], sc0, w0);
      decode8(dp1[ib * 4 + c], sc1, w1);
      int i4 = ib * 8 + c * 2;
      #pragma unroll
      for (int tok = 0; tok < TT; ++tok) {
        float4 a = av[tok][i4], b = av[tok][i4 + 1];
        a0[tok] += w0[0]*a.x + w0[1]*a.y + w0[2]*a.z + w0[3]*a.w
                 + w0[4]*b.x + w0[5]*b.y + w0[6]*b.z + w0[7]*b.w;
        a1[tok] += w1[0]*a.x + w1[1]*a.y + w1[2]*a.z + w1[3]*a.w
                 + w1[4]*b.x + w1[5]*b.y + w1[6]*b.z + w1[7]*b.w;
      }
    }
  }
  #pragma unroll
  for (int tok = 0; tok < TT; ++tok) {
    if (tok < n) {
      int entry = s_entry[tok]; int t = entry >> 3, j = entry & 7;
      size_t slot = (size_t)t * kk + j;
      partial[slot * HH + h0] = a0[tok];
      partial[slot * HH + h1] = a1[tok];
    }
  }
}

__global__ void combine_kernel(const float* __restrict__ partial, const float* __restrict__ route,
                               const float* __restrict__ dbias, const int* __restrict__ dk,
                               float* __restrict__ out, int E) {
  int t = blockIdx.y;
  int h = blockIdx.x * 256 + threadIdx.x;
  int kk = *dk; if (kk > KMAX) kk = KMAX; if (kk < 1) kk = 1;
  float s = 0.f;
  for (int j = 0; j < kk; ++j) s += partial[((size_t)t * kk + j) * HH + h];
  for (int e = 0; e < E; ++e) s += route[t * E + e] * dbias[(size_t)e * HH + h];
  out[(size_t)t * HH + h] = s;
}

extern "C" void kernel_launch(void* const* d_in, const int* in_sizes, int n_in,
                              void* d_out, int out_size, void* d_ws, size_t ws_size,
                              hipStream_t stream) {
  const float* hs    = (const float*)d_in[0];
  const float* rl    = (const float*)d_in[1];
  const int*   gblk  = (const int*)d_in[2];
  const int*   gscl  = (const int*)d_in[3];
  const float* gbias = (const float*)d_in[4];
  const int*   ublk  = (const int*)d_in[5];
  const int*   uscl  = (const int*)d_in[6];
  const float* ubias = (const float*)d_in[7];
  const int*   dblk  = (const int*)d_in[8];
  const int*   dscl  = (const int*)d_in[9];
  const float* dbias = (const float*)d_in[10];
  const int*   dk    = (const int*)d_in[11];

  long s0 = in_sizes[0], s1 = in_sizes[1], s2 = in_sizes[2], s4 = in_sizes[4];
  int H = (int)(2 * s2 / s4);       // = 1024
  int T = (int)(s0 / H);            // = 1024
  int E = (int)(s1 / T);            // = 8
  // I = s4 / E = 1024 (compile-time II assumed)

  char* w = (char*)d_ws;
  auto alloc = [&](size_t bytes) { char* p = w; w += (bytes + 255) & ~size_t(255); return p; };
  float* route   = (float*)alloc(sizeof(float) * (size_t)T * E);
  int*   tidx    = (int*)  alloc(sizeof(int)   * (size_t)T * KMAX);
  float* tw      = (float*)alloc(sizeof(float) * (size_t)T * KMAX);
  int*   counts  = (int*)  alloc(sizeof(int)   * (size_t)E);
  int*   lists   = (int*)  alloc(sizeof(int)   * (size_t)E * T);
  float* act     = (float*)alloc(sizeof(float) * (size_t)T * KMAX * II);
  float* partial = (float*)alloc(sizeof(float) * (size_t)T * KMAX * HH);

  int tilesPerE = (T + TT - 1) / TT;

  routing_kernel<<<dim3((T + 255) / 256), 256, 0, stream>>>(rl, dk, T, E, route, tidx, tw);
  build_lists<<<dim3(E), 64, 0, stream>>>(tidx, dk, T, lists, counts);
  gate_up_act<<<dim3(E * tilesPerE, II / 512), 256, 0, stream>>>(
      hs, gblk, gscl, gbias, ublk, uscl, ubias, lists, counts, tw, dk, act, T, tilesPerE);
  down_proj<<<dim3(E * tilesPerE, HH / 512), 256, 0, stream>>>(
      act, dblk, dscl, lists, counts, dk, partial, T, tilesPerE);
  combine_kernel<<<dim3(HH / 256, T), 256, 0, stream>>>(partial, route, dbias, dk, (float*)d_out, E);
}

// Round 2
// 153.695 us; speedup vs baseline: 5.9588x; 5.9588x over previous
//
#include <hip/hip_runtime.h>
#include <cstdint>
#include <cstddef>

typedef __bf16 bf16x8 __attribute__((ext_vector_type(8)));
typedef float f32x4 __attribute__((ext_vector_type(4)));

constexpr int HH = 1024;   // hidden dim
constexpr int II = 1024;   // intermediate dim
constexpr int KMAX = 2;
constexpr int EMAX = 8;
constexpr float FALPHA = 1.702f;
constexpr float FLIMIT = 7.0f;

// fp4 e2m1 decode: returns value*2 as float with sign
__device__ __forceinline__ float fp4v(int c) {
  int mag = c & 7;
  int e = mag >> 1, m = mag & 1;
  int k = e ? ((2 + m) << (e - 1)) : mag;         // |value|*2
  return __int_as_float(__float_as_int((float)k) | ((c & 8) << 28));
}
// 0.5 * 2^(s-127) = 2^(s-128)
__device__ __forceinline__ float sc_half(int s) {
  return __uint_as_float((unsigned)(s - 1) << 23);
}
// one int4 (4 int32, each one byte = 2 nibbles) -> 8 bf16 weights (exact)
__device__ __forceinline__ bf16x8 decode8(int4 b, float sc) {
  int v0 = b.x, v1 = b.y, v2 = b.z, v3 = b.w;
  bf16x8 r;
  r[0] = (__bf16)(fp4v(v0 & 15) * sc); r[1] = (__bf16)(fp4v((v0 >> 4) & 15) * sc);
  r[2] = (__bf16)(fp4v(v1 & 15) * sc); r[3] = (__bf16)(fp4v((v1 >> 4) & 15) * sc);
  r[4] = (__bf16)(fp4v(v2 & 15) * sc); r[5] = (__bf16)(fp4v((v2 >> 4) & 15) * sc);
  r[6] = (__bf16)(fp4v(v3 & 15) * sc); r[7] = (__bf16)(fp4v((v3 >> 4) & 15) * sc);
  return r;
}

__device__ __forceinline__ void gll16(const void* g, void* l) {
  __builtin_amdgcn_global_load_lds(
      (const __attribute__((address_space(1))) void*)g,
      (__attribute__((address_space(3))) void*)l, 16, 0, 0);
}

// ---------------- routing ----------------
__global__ void routing_kernel(const float* __restrict__ logits, const int* __restrict__ dk,
                               int T, int E, float* __restrict__ route,
                               int* __restrict__ tidx, float* __restrict__ tw) {
  int t = blockIdx.x * blockDim.x + threadIdx.x;
  if (t >= T) return;
  int kk = *dk; if (kk > KMAX) kk = KMAX; if (kk < 1) kk = 1;
  int EE = E > EMAX ? EMAX : E;
  float v[EMAX]; bool used[EMAX];
  for (int e = 0; e < EE; ++e) { v[e] = logits[t * E + e]; used[e] = false; route[t * E + e] = 0.f; }
  float tv[KMAX]; int ti[KMAX];
  for (int j = 0; j < kk; ++j) {
    float best = -3.4e38f; int bi = 0;
    for (int e = 0; e < EE; ++e) if (!used[e] && v[e] > best) { best = v[e]; bi = e; }
    used[bi] = true; tv[j] = best; ti[j] = bi;
  }
  float mx = tv[0], ssum = 0.f, wj[KMAX];
  for (int j = 0; j < kk; ++j) { wj[j] = __expf(tv[j] - mx); ssum += wj[j]; }
  for (int j = 0; j < kk; ++j) {
    float wv = wj[j] / ssum;
    route[t * E + ti[j]] = wv;
    tidx[t * kk + j] = ti[j];
    tw[t * kk + j] = wv;
  }
}

__global__ void build_lists(const int* __restrict__ tidx, const int* __restrict__ dk,
                            int T, int* __restrict__ lists, int* __restrict__ counts) {
  int e = blockIdx.x;
  int lane = threadIdx.x;  // 64 threads = 1 wave
  int kk = *dk; if (kk > KMAX) kk = KMAX; if (kk < 1) kk = 1;
  int cnt = 0;
  for (int base = 0; base < T; base += 64) {
    int t = base + lane;
    int j = -1;
    if (t < T) {
      for (int q = 0; q < kk; ++q) if (tidx[t * kk + q] == e) j = q;
    }
    unsigned long long m = __ballot(j >= 0);
    if (j >= 0) {
      int pre = __popcll(m & ((1ull << lane) - 1ull));
      lists[e * T + cnt + pre] = (t << 3) | j;
    }
    cnt += __popcll(m);
  }
  if (lane == 0) counts[e] = cnt;
}

// ---------------- hs fp32 -> bf16 ----------------
__global__ void convert_hs(const float* __restrict__ hs, __bf16* __restrict__ hsb, int n8) {
  int t = blockIdx.x * 256 + threadIdx.x;
  if (t >= n8) return;
  const float4* p = (const float4*)hs + (size_t)t * 2;
  float4 a = p[0], b = p[1];
  bf16x8 r;
  r[0] = (__bf16)a.x; r[1] = (__bf16)a.y; r[2] = (__bf16)a.z; r[3] = (__bf16)a.w;
  r[4] = (__bf16)b.x; r[5] = (__bf16)b.y; r[6] = (__bf16)b.z; r[7] = (__bf16)b.w;
  *(bf16x8*)(hsb + (size_t)t * 8) = r;
}

// ---------------- gate+up MFMA GEMM (fused dequant) ----------------
// tile: M=256 tokens x N=64 (32 i's x {gate,up}), BK=64, 4 waves (2x2), wave tile 128x32
__global__ __launch_bounds__(256) void gemm_gate_up(
    const __bf16* __restrict__ hsb,
    const int* __restrict__ gblk, const int* __restrict__ gscl, const float* __restrict__ gbias,
    const int* __restrict__ ublk, const int* __restrict__ uscl, const float* __restrict__ ubias,
    const int* __restrict__ lists, const int* __restrict__ counts,
    const float* __restrict__ tw, const int* __restrict__ dk,
    __bf16* __restrict__ act, int T)
{
  int e = blockIdx.x >> 2, mtile = blockIdx.x & 3;
  int cnt = counts[e];
  int n_valid = cnt - mtile * 256;
  if (n_valid <= 0) return;
  if (n_valid > 256) n_valid = 256;
  int kk = *dk; if (kk > KMAX) kk = KMAX; if (kk < 1) kk = 1;

  __shared__ int s_tok[256];
  __shared__ bf16x8 Alds[2048];   // 256 rows x 8 chunks (swizzled), 32 KB
  __shared__ bf16x8 Blds[512];    // 64 rows x 8 chunks (swizzled), 8 KB

  int tid = threadIdx.x;
  {
    int idx = mtile * 256 + tid;
    s_tok[tid] = lists[e * T + (idx < cnt ? idx : mtile * 256)];
  }
  __syncthreads();

  int lane = tid & 63, w = tid >> 6;
  int wr = w >> 1, wc = w & 1;

  // A staging: wave w covers segs w*8..w*8+7; lane l: row r=seg*8+l/8, src chunk c=(l%8)^(l/8)
  int cA = (lane & 7) ^ (lane >> 3);
  unsigned aOff[8];
  #pragma unroll
  for (int q = 0; q < 8; ++q) {
    int r = w * 64 + q * 8 + (lane >> 3);
    int tok = s_tok[r] >> 3;
    aOff[q] = (unsigned)tok * (HH * 2) + (unsigned)cA * 16;
  }

  // B decode meta: slots s = tid, tid+256: r=s/8, cs=s%8, c=cs^(r&7)
  int ibase = blockIdx.y * 32;
  const int4* bsrc0; const int4* bsrc1;
  const int* bscl0; const int* bscl1;
  int bc0, bc1;
  {
    int s = tid, r = s >> 3, cs = s & 7;
    bc0 = cs ^ (r & 7);
    int pairIdx = r >> 5, sub = r & 31, isUp = (sub >> 4) & 1;
    int i = ibase + pairIdx * 16 + (sub & 15);
    const int* blkb = isUp ? ublk : gblk;
    const int* sclb = isUp ? uscl : gscl;
    bsrc0 = (const int4*)(blkb + ((size_t)e * II + i) * (HH / 2));
    bscl0 = sclb + ((size_t)e * II + i) * (HH / 32);
  }
  {
    int s = tid + 256, r = s >> 3, cs = s & 7;
    bc1 = cs ^ (r & 7);
    int pairIdx = r >> 5, sub = r & 31, isUp = (sub >> 4) & 1;
    int i = ibase + pairIdx * 16 + (sub & 15);
    const int* blkb = isUp ? ublk : gblk;
    const int* sclb = isUp ? uscl : gscl;
    bsrc1 = (const int4*)(blkb + ((size_t)e * II + i) * (HH / 2));
    bscl1 = sclb + ((size_t)e * II + i) * (HH / 32);
  }

  int4 pb0 = bsrc0[bc0], pb1 = bsrc1[bc1];
  float ps0 = sc_half(bscl0[bc0 >> 2]);
  float ps1 = sc_half(bscl1[bc1 >> 2]);

  f32x4 acc[8][2];
  #pragma unroll
  for (int a = 0; a < 8; ++a) { acc[a][0] = (f32x4)0.f; acc[a][1] = (f32x4)0.f; }

  for (int kt = 0; kt < HH / 64; ++kt) {
    // stage A (global -> LDS, linear dest, pre-swizzled source)
    #pragma unroll
    for (int q = 0; q < 8; ++q) {
      gll16((const char*)hsb + aOff[q] + kt * 128, (char*)Alds + (w * 8 + q) * 1024);
    }
    // decode current B regs -> LDS (linear conflict-free writes)
    bf16x8 d0 = decode8(pb0, ps0), d1 = decode8(pb1, ps1);
    Blds[tid] = d0;
    Blds[tid + 256] = d1;
    __syncthreads();
    // prefetch next B (in flight during MFMA phase)
    if (kt < HH / 64 - 1) {
      pb0 = bsrc0[(kt + 1) * 8 + bc0];
      pb1 = bsrc1[(kt + 1) * 8 + bc1];
      ps0 = sc_half(bscl0[(kt + 1) * 2 + (bc0 >> 2)]);
      ps1 = sc_half(bscl1[(kt + 1) * 2 + (bc1 >> 2)]);
    }
    // compute
    #pragma unroll
    for (int kq = 0; kq < 2; ++kq) {
      int kg = kq * 4 + (lane >> 4);
      int n0 = wc * 32 + (lane & 15);
      bf16x8 b0 = Blds[n0 * 8 + (kg ^ (n0 & 7))];
      int n1 = n0 + 16;
      bf16x8 b1 = Blds[n1 * 8 + (kg ^ (n1 & 7))];
      #pragma unroll
      for (int fm = 0; fm < 8; ++fm) {
        int m = wr * 128 + fm * 16 + (lane & 15);
        bf16x8 a = Alds[m * 8 + (kg ^ (m & 7))];
        acc[fm][0] = __builtin_amdgcn_mfma_f32_16x16x32_bf16(a, b0, acc[fm][0], 0, 0, 0);
        acc[fm][1] = __builtin_amdgcn_mfma_f32_16x16x32_bf16(a, b1, acc[fm][1], 0, 0, 0);
      }
    }
    __syncthreads();
  }

  // epilogue: pair gate (fn=0) / up (fn=1), GLU, fold route weight, store bf16
  int i_col = ibase + wc * 16 + (lane & 15);
  float gb = gbias[e * II + i_col], ub = ubias[e * II + i_col];
  int rbase = wr * 128 + ((lane >> 4) << 2);
  #pragma unroll
  for (int fm = 0; fm < 8; ++fm) {
    #pragma unroll
    for (int rg = 0; rg < 4; ++rg) {
      int mloc = rbase + fm * 16 + rg;
      if (mloc < n_valid) {
        int entry = s_tok[mloc];
        int t = entry >> 3, j = entry & 7;
        float wv = tw[t * kk + j];
        float g = fminf(acc[fm][0][rg] + gb, FLIMIT);
        float u = fminf(fmaxf(acc[fm][1][rg] + ub, -FLIMIT), FLIMIT);
        float glu = g / (1.f + __expf(-FALPHA * g));
        float val = (u + 1.f) * glu * wv;
        act[((size_t)t * kk + j) * II + i_col] = (__bf16)val;
      }
    }
  }
}

// ---------------- down MFMA GEMM (fused dequant) ----------------
// tile: M=256 slots x N=64 h's, BK=64, 4 waves (2x2), wave tile 128x32
__global__ __launch_bounds__(256) void gemm_down(
    const __bf16* __restrict__ act,
    const int* __restrict__ dblk, const int* __restrict__ dscl,
    const int* __restrict__ lists, const int* __restrict__ counts,
    const int* __restrict__ dk,
    float* __restrict__ partial, int T)
{
  int e = blockIdx.x >> 2, mtile = blockIdx.x & 3;
  int cnt = counts[e];
  int n_valid = cnt - mtile * 256;
  if (n_valid <= 0) return;
  if (n_valid > 256) n_valid = 256;
  int kk = *dk; if (kk > KMAX) kk = KMAX; if (kk < 1) kk = 1;

  __shared__ int s_tok[256];
  __shared__ bf16x8 Alds[2048];
  __shared__ bf16x8 Blds[512];

  int tid = threadIdx.x;
  {
    int idx = mtile * 256 + tid;
    s_tok[tid] = lists[e * T + (idx < cnt ? idx : mtile * 256)];
  }
  __syncthreads();

  int lane = tid & 63, w = tid >> 6;
  int wr = w >> 1, wc = w & 1;

  int cA = (lane & 7) ^ (lane >> 3);
  unsigned aOff[8];
  #pragma unroll
  for (int q = 0; q < 8; ++q) {
    int r = w * 64 + q * 8 + (lane >> 3);
    int entry = s_tok[r];
    int slot = (entry >> 3) * kk + (entry & 7);
    aOff[q] = (unsigned)slot * (II * 2) + (unsigned)cA * 16;
  }

  int hbase = blockIdx.y * 64;
  const int4* bsrc0; const int4* bsrc1;
  const int* bscl0; const int* bscl1;
  int bc0, bc1;
  {
    int s = tid, r = s >> 3, cs = s & 7;
    bc0 = cs ^ (r & 7);
    int h = hbase + r;
    bsrc0 = (const int4*)(dblk + ((size_t)e * HH + h) * (II / 2));
    bscl0 = dscl + ((size_t)e * HH + h) * (II / 32);
  }
  {
    int s = tid + 256, r = s >> 3, cs = s & 7;
    bc1 = cs ^ (r & 7);
    int h = hbase + r;
    bsrc1 = (const int4*)(dblk + ((size_t)e * HH + h) * (II / 2));
    bscl1 = dscl + ((size_t)e * HH + h) * (II / 32);
  }

  int4 pb0 = bsrc0[bc0], pb1 = bsrc1[bc1];
  float ps0 = sc_half(bscl0[bc0 >> 2]);
  float ps1 = sc_half(bscl1[bc1 >> 2]);

  f32x4 acc[8][2];
  #pragma unroll
  for (int a = 0; a < 8; ++a) { acc[a][0] = (f32x4)0.f; acc[a][1] = (f32x4)0.f; }

  for (int kt = 0; kt < II / 64; ++kt) {
    #pragma unroll
    for (int q = 0; q < 8; ++q) {
      gll16((const char*)act + aOff[q] + kt * 128, (char*)Alds + (w * 8 + q) * 1024);
    }
    bf16x8 d0 = decode8(pb0, ps0), d1 = decode8(pb1, ps1);
    Blds[tid] = d0;
    Blds[tid + 256] = d1;
    __syncthreads();
    if (kt < II / 64 - 1) {
      pb0 = bsrc0[(kt + 1) * 8 + bc0];
      pb1 = bsrc1[(kt + 1) * 8 + bc1];
      ps0 = sc_half(bscl0[(kt + 1) * 2 + (bc0 >> 2)]);
      ps1 = sc_half(bscl1[(kt + 1) * 2 + (bc1 >> 2)]);
    }
    #pragma unroll
    for (int kq = 0; kq < 2; ++kq) {
      int kg = kq * 4 + (lane >> 4);
      int n0 = wc * 32 + (lane & 15);
      bf16x8 b0 = Blds[n0 * 8 + (kg ^ (n0 & 7))];
      int n1 = n0 + 16;
      bf16x8 b1 = Blds[n1 * 8 + (kg ^ (n1 & 7))];
      #pragma unroll
      for (int fm = 0; fm < 8; ++fm) {
        int m = wr * 128 + fm * 16 + (lane & 15);
        bf16x8 a = Alds[m * 8 + (kg ^ (m & 7))];
        acc[fm][0] = __builtin_amdgcn_mfma_f32_16x16x32_bf16(a, b0, acc[fm][0], 0, 0, 0);
        acc[fm][1] = __builtin_amdgcn_mfma_f32_16x16x32_bf16(a, b1, acc[fm][1], 0, 0, 0);
      }
    }
    __syncthreads();
  }

  int rbase = wr * 128 + ((lane >> 4) << 2);
  int h0 = hbase + wc * 32 + (lane & 15);
  #pragma unroll
  for (int fm = 0; fm < 8; ++fm) {
    #pragma unroll
    for (int rg = 0; rg < 4; ++rg) {
      int mloc = rbase + fm * 16 + rg;
      if (mloc < n_valid) {
        int entry = s_tok[mloc];
        int t = entry >> 3, j = entry & 7;
        size_t slot = (size_t)t * kk + j;
        partial[slot * HH + h0] = acc[fm][0][rg];
        partial[slot * HH + h0 + 16] = acc[fm][1][rg];
      }
    }
  }
}

// ---------------- combine ----------------
__global__ void combine_kernel(const float* __restrict__ partial, const float* __restrict__ route,
                               const float* __restrict__ dbias, const int* __restrict__ dk,
                               float* __restrict__ out, int E) {
  int t = blockIdx.y;
  int h = blockIdx.x * 256 + threadIdx.x;
  int kk = *dk; if (kk > KMAX) kk = KMAX; if (kk < 1) kk = 1;
  float s = 0.f;
  for (int j = 0; j < kk; ++j) s += partial[((size_t)t * kk + j) * HH + h];
  for (int e = 0; e < E; ++e) s += route[t * E + e] * dbias[(size_t)e * HH + h];
  out[(size_t)t * HH + h] = s;
}

extern "C" void kernel_launch(void* const* d_in, const int* in_sizes, int n_in,
                              void* d_out, int out_size, void* d_ws, size_t ws_size,
                              hipStream_t stream) {
  const float* hs    = (const float*)d_in[0];
  const float* rl    = (const float*)d_in[1];
  const int*   gblk  = (const int*)d_in[2];
  const int*   gscl  = (const int*)d_in[3];
  const float* gbias = (const float*)d_in[4];
  const int*   ublk  = (const int*)d_in[5];
  const int*   uscl  = (const int*)d_in[6];
  const float* ubias = (const float*)d_in[7];
  const int*   dblk  = (const int*)d_in[8];
  const int*   dscl  = (const int*)d_in[9];
  const float* dbias = (const float*)d_in[10];
  const int*   dk    = (const int*)d_in[11];

  long s0 = in_sizes[0], s1 = in_sizes[1], s2 = in_sizes[2], s4 = in_sizes[4];
  int H = (int)(2 * s2 / s4);       // = 1024
  int T = (int)(s0 / H);            // = 1024
  int E = (int)(s1 / T);            // = 8

  char* w = (char*)d_ws;
  auto alloc = [&](size_t bytes) { char* p = w; w += (bytes + 255) & ~size_t(255); return p; };
  float*  route   = (float*)alloc(sizeof(float) * (size_t)T * E);
  int*    tidx    = (int*)  alloc(sizeof(int)   * (size_t)T * KMAX);
  float*  twp     = (float*)alloc(sizeof(float) * (size_t)T * KMAX);
  int*    counts  = (int*)  alloc(sizeof(int)   * (size_t)E);
  int*    lists   = (int*)  alloc(sizeof(int)   * (size_t)E * T);
  __bf16* hsb     = (__bf16*)alloc(sizeof(__bf16) * (size_t)T * HH);
  __bf16* act     = (__bf16*)alloc(sizeof(__bf16) * (size_t)T * KMAX * II);
  float*  partial = (float*)alloc(sizeof(float) * (size_t)T * KMAX * HH);

  routing_kernel<<<dim3((T + 255) / 256), 256, 0, stream>>>(rl, dk, T, E, route, tidx, twp);
  build_lists<<<dim3(E), 64, 0, stream>>>(tidx, dk, T, lists, counts);
  convert_hs<<<dim3((T * HH / 8 + 255) / 256), 256, 0, stream>>>(hs, hsb, T * HH / 8);
  gemm_gate_up<<<dim3(E * 4, II / 32), 256, 0, stream>>>(
      hsb, gblk, gscl, gbias, ublk, uscl, ubias, lists, counts, twp, dk, act, T);
  gemm_down<<<dim3(E * 4, HH / 64), 256, 0, stream>>>(
      act, dblk, dscl, lists, counts, dk, partial, T);
  combine_kernel<<<dim3(HH / 256, T), 256, 0, stream>>>(partial, route, dbias, dk, (float*)d_out, E);
}

// Round 3
// 106.736 us; speedup vs baseline: 8.5805x; 1.4400x over previous
//
#include <hip/hip_runtime.h>
#include <cstdint>
#include <cstddef>

typedef __bf16 bf16x8 __attribute__((ext_vector_type(8)));
typedef float f32x4 __attribute__((ext_vector_type(4)));
typedef unsigned short u16x2 __attribute__((ext_vector_type(2)));

constexpr int HH = 1024;   // hidden dim
constexpr int II = 1024;   // intermediate dim
constexpr int KMAX = 2;
constexpr int EMAX = 8;
constexpr int GU_TILES = 24;   // 2048/128 + 8
constexpr int DN_TILES = 40;   // 2048/64 + 8
constexpr float FALPHA = 1.702f;
constexpr float FLIMIT = 7.0f;

// ---- fp4(e2m1) -> bf16 decode via v_perm byte tables ----
// weight order within an 8-group is PERMUTED: p = [0,2,4,6,1,3,5,7]
// (element j holds logical weight p(j)); A-side data uses the same perm.
// zero is encoded as 2^-87 (0x1400) so the packed exponent-add scale is branchless.
__device__ __forceinline__ unsigned pk_add16(unsigned a, unsigned b) {
  u16x2 x, y;
  __builtin_memcpy(&x, &a, 4); __builtin_memcpy(&y, &b, 4);
  u16x2 r = x + y;
  unsigned o; __builtin_memcpy(&o, &r, 4); return o;
}

__device__ __forceinline__ int4 decode_chunk(int4 raw, unsigned addk) {
  unsigned p = (unsigned)raw.x | ((unsigned)raw.y << 8) |
               ((unsigned)raw.z << 16) | ((unsigned)raw.w << 24);
  unsigned q = p >> 4;
  unsigned me = p & 0x07070707u, mo = q & 0x07070707u;
  unsigned se = p & 0x08080808u, so = q & 0x08080808u;
  unsigned hiE = __builtin_amdgcn_perm(0x40404040u, 0x3F3F3F14u, me) | (se << 4);
  unsigned hiO = __builtin_amdgcn_perm(0x40404040u, 0x3F3F3F14u, mo) | (so << 4);
  unsigned loE = __builtin_amdgcn_perm(0xC0804000u, 0xC0800000u, me);
  unsigned loO = __builtin_amdgcn_perm(0xC0804000u, 0xC0800000u, mo);
  int4 out;
  out.x = (int)pk_add16(__builtin_amdgcn_perm(hiE, loE, 0x05010400u), addk); // w2:w0
  out.y = (int)pk_add16(__builtin_amdgcn_perm(hiE, loE, 0x07030602u), addk); // w6:w4
  out.z = (int)pk_add16(__builtin_amdgcn_perm(hiO, loO, 0x05010400u), addk); // w3:w1
  out.w = (int)pk_add16(__builtin_amdgcn_perm(hiO, loO, 0x07030602u), addk); // w7:w5
  return out;
}

__device__ __forceinline__ unsigned make_addk(int s) {
  int k = s - 127;
  unsigned t = ((unsigned)(k << 7)) & 0xFFFFu;
  return t | (t << 16);
}

__device__ __forceinline__ void gll16(const void* g, void* l) {
  __builtin_amdgcn_global_load_lds(
      (const __attribute__((address_space(1))) void*)g,
      (__attribute__((address_space(3))) void*)l, 16, 0, 0);
}

// ---------------- routing ----------------
__global__ void routing_kernel(const float* __restrict__ logits, const int* __restrict__ dk,
                               int T, int E, float* __restrict__ route,
                               int* __restrict__ tidx, float* __restrict__ tw) {
  int t = blockIdx.x * blockDim.x + threadIdx.x;
  if (t >= T) return;
  int kk = *dk; if (kk > KMAX) kk = KMAX; if (kk < 1) kk = 1;
  int EE = E > EMAX ? EMAX : E;
  float v[EMAX]; bool used[EMAX];
  for (int e = 0; e < EE; ++e) { v[e] = logits[t * E + e]; used[e] = false; route[t * E + e] = 0.f; }
  float tv[KMAX]; int ti[KMAX];
  for (int j = 0; j < kk; ++j) {
    float best = -3.4e38f; int bi = 0;
    for (int e = 0; e < EE; ++e) if (!used[e] && v[e] > best) { best = v[e]; bi = e; }
    used[bi] = true; tv[j] = best; ti[j] = bi;
  }
  float mx = tv[0], ssum = 0.f, wj[KMAX];
  for (int j = 0; j < kk; ++j) { wj[j] = __expf(tv[j] - mx); ssum += wj[j]; }
  for (int j = 0; j < kk; ++j) {
    float wv = wj[j] / ssum;
    route[t * E + ti[j]] = wv;
    tidx[t * kk + j] = ti[j];
    tw[t * kk + j] = wv;
  }
}

__global__ void build_lists(const int* __restrict__ tidx, const int* __restrict__ dk,
                            int T, int* __restrict__ lists, int* __restrict__ counts) {
  int e = blockIdx.x;
  int lane = threadIdx.x;  // 64 threads = 1 wave
  int kk = *dk; if (kk > KMAX) kk = KMAX; if (kk < 1) kk = 1;
  int cnt = 0;
  for (int base = 0; base < T; base += 64) {
    int t = base + lane;
    int j = -1;
    if (t < T) {
      for (int q = 0; q < kk; ++q) if (tidx[t * kk + q] == e) j = q;
    }
    unsigned long long m = __ballot(j >= 0);
    if (j >= 0) {
      int pre = __popcll(m & ((1ull << lane) - 1ull));
      lists[e * T + cnt + pre] = (t << 3) | j;
    }
    cnt += __popcll(m);
  }
  if (lane == 0) counts[e] = cnt;
}

__global__ void build_tiles(const int* __restrict__ counts, int E,
                            int* __restrict__ tabGU, int* __restrict__ tabDN) {
  if (threadIdx.x == 0 && blockIdx.x == 0) {
    int g = 0, d = 0;
    for (int e = 0; e < E && e < EMAX; ++e) {
      int c = counts[e];
      for (int m = 0; m * 128 < c && g < GU_TILES; ++m) tabGU[g++] = (e << 16) | m;
      for (int m = 0; m * 64 < c && d < DN_TILES; ++m) tabDN[d++] = (e << 16) | m;
    }
    for (; g < GU_TILES; ++g) tabGU[g] = -1;
    for (; d < DN_TILES; ++d) tabDN[d] = -1;
  }
}

// ---------------- hs fp32 -> bf16, permuted 8-groups [0,2,4,6,1,3,5,7] ----------------
__global__ void convert_hs(const float* __restrict__ hs, __bf16* __restrict__ hsb, int n8) {
  int g = blockIdx.x * 256 + threadIdx.x;
  if (g >= n8) return;
  const float4* p = (const float4*)hs + (size_t)g * 2;
  float4 a = p[0], b = p[1];
  bf16x8 r;
  r[0] = (__bf16)a.x; r[1] = (__bf16)a.z; r[2] = (__bf16)b.x; r[3] = (__bf16)b.z;
  r[4] = (__bf16)a.y; r[5] = (__bf16)a.w; r[6] = (__bf16)b.y; r[7] = (__bf16)b.w;
  *(bf16x8*)(hsb + (size_t)g * 8) = r;
}

// ---------------- gate+up MFMA GEMM (fused perm-decode, dbuf, 1 barrier/K) -------------
// M=128 slots, N=128 (64 i x {gate,up}), BK=64, 256 thr, waves 2x2, wave tile 64x64
__global__ __launch_bounds__(256, 2) void gemm_gate_up(
    const __bf16* __restrict__ hsb,
    const int* __restrict__ gblk, const int* __restrict__ gscl, const float* __restrict__ gbias,
    const int* __restrict__ ublk, const int* __restrict__ uscl, const float* __restrict__ ubias,
    const int* __restrict__ lists, const int* __restrict__ counts,
    const float* __restrict__ tw, const int* __restrict__ dk,
    const int* __restrict__ tab,
    __bf16* __restrict__ act, int T)
{
  int te = tab[blockIdx.x];
  if (te < 0) return;
  int e = te >> 16, mtile = te & 0xFFFF;
  int cnt = counts[e];
  int n_valid = cnt - mtile * 128;
  if (n_valid <= 0) return;
  if (n_valid > 128) n_valid = 128;
  int kk = *dk; if (kk > KMAX) kk = KMAX; if (kk < 1) kk = 1;

  __shared__ int s_tok[128];
  __shared__ char Abuf[2][16384];  // [m 0..127][phys chunk 0..7 of 16B], chunk phys = c^(m&7)
  __shared__ char Bbuf[2][16384];  // transposed: [chunk 0..7][n 0..127] * 16B

  int tid = threadIdx.x;
  if (tid < 128) {
    int idx = mtile * 128 + tid;
    s_tok[tid] = lists[e * T + (idx < cnt ? idx : mtile * 128)];
  }
  __syncthreads();

  int lane = tid & 63, w = tid >> 6;
  int r15 = lane & 15, sw = lane & 7;
  int wr = w >> 1, wc = w & 1;

  // --- A staging meta: wave w stages rows [w*32, w*32+32), 4 gll16 ---
  int cA = (lane & 7) ^ (lane >> 3);
  size_t aOff[4];
  #pragma unroll
  for (int q = 0; q < 4; ++q) {
    int row = w * 32 + q * 8 + (lane >> 3);
    int tok = s_tok[row] >> 3;
    aOff[q] = (size_t)tok * (HH * 2) + (size_t)cA * 16;
  }

  // --- B decode meta: thread handles row r=tid>>1, chunks c4..c4+3 ---
  int rB = tid >> 1, c4 = (tid & 1) * 4;
  int gu = (rB >> 4) & 1;
  int iLoc = (rB & 15) | ((rB >> 5) << 4);
  int ibase = blockIdx.y * 64;
  int i_row = ibase + iLoc;
  const int* blk = gu ? ublk : gblk;
  const int* scl = gu ? uscl : gscl;
  const int4* bp = (const int4*)(blk + ((size_t)e * II + i_row) * (HH / 2));
  const int* sp = scl + ((size_t)e * II + i_row) * (HH / 32);

  f32x4 acc[4][4];
  #pragma unroll
  for (int a = 0; a < 4; ++a)
    #pragma unroll
    for (int b = 0; b < 4; ++b) acc[a][b] = (f32x4)0.f;

  // ---- prologue: tile 0 ----
  #pragma unroll
  for (int q = 0; q < 4; ++q)
    gll16((const char*)hsb + aOff[q], Abuf[0] + w * 4096 + q * 1024);
  {
    int4 rw[4];
    #pragma unroll
    for (int j = 0; j < 4; ++j) rw[j] = bp[c4 + j];
    unsigned addk = make_addk(sp[tid & 1]);
    #pragma unroll
    for (int j = 0; j < 4; ++j)
      *(int4*)(Bbuf[0] + (c4 + j) * 2048 + rB * 16) = decode_chunk(rw[j], addk);
  }
  __syncthreads();

  constexpr int NK = HH / 64;  // 16
  for (int kt = 0; kt < NK; ++kt) {
    char* An = Abuf[(kt + 1) & 1];
    char* Bn = Bbuf[(kt + 1) & 1];
    const char* Ac = Abuf[kt & 1];
    const char* Bc = Bbuf[kt & 1];
    int4 rw[4]; unsigned addk = 0;
    if (kt < NK - 1) {
      #pragma unroll
      for (int q = 0; q < 4; ++q)
        gll16((const char*)hsb + aOff[q] + (kt + 1) * 128, An + w * 4096 + q * 1024);
      #pragma unroll
      for (int j = 0; j < 4; ++j) rw[j] = bp[(kt + 1) * 8 + c4 + j];
      addk = make_addk(sp[(kt + 1) * 2 + (tid & 1)]);
    }
    // ---- MFMA on current tile ----
    #pragma unroll
    for (int kq = 0; kq < 2; ++kq) {
      int kc = kq * 4 + (lane >> 4);
      bf16x8 bf[4];
      #pragma unroll
      for (int fn = 0; fn < 4; ++fn)
        bf[fn] = *(const bf16x8*)(Bc + kc * 2048 + (wc * 64 + fn * 16 + r15) * 16);
      #pragma unroll
      for (int fm = 0; fm < 4; ++fm) {
        int m = wr * 64 + fm * 16 + r15;
        bf16x8 af = *(const bf16x8*)(Ac + m * 128 + ((kc ^ sw) * 16));
        #pragma unroll
        for (int fn = 0; fn < 4; ++fn)
          acc[fm][fn] = __builtin_amdgcn_mfma_f32_16x16x32_bf16(af, bf[fn], acc[fm][fn], 0, 0, 0);
      }
    }
    if (kt < NK - 1) {
      #pragma unroll
      for (int j = 0; j < 4; ++j)
        *(int4*)(Bn + (c4 + j) * 2048 + rB * 16) = decode_chunk(rw[j], addk);
    }
    __syncthreads();
  }

  // ---- epilogue: fn pairs (0,1)=(g,u) i+0..15, (2,3) i+16..31; fold GLU+route ----
  #pragma unroll
  for (int fp = 0; fp < 2; ++fp) {
    int i_log = ibase + wc * 32 + fp * 16 + r15;
    float gb = gbias[e * II + i_log], ub = ubias[e * II + i_log];
    int i_phys = (i_log & ~7) | ((r15 & 1) << 2) | ((r15 & 7) >> 1);
    #pragma unroll
    for (int fm = 0; fm < 4; ++fm) {
      #pragma unroll
      for (int rg = 0; rg < 4; ++rg) {
        int mloc = wr * 64 + fm * 16 + (lane >> 4) * 4 + rg;
        if (mloc < n_valid) {
          int entry = s_tok[mloc];
          int t = entry >> 3, j = entry & 7;
          float wv = tw[t * kk + j];
          float g = fminf(acc[fm][fp * 2][rg] + gb, FLIMIT);
          float u = fminf(fmaxf(acc[fm][fp * 2 + 1][rg] + ub, -FLIMIT), FLIMIT);
          float glu = g / (1.f + __expf(-FALPHA * g));
          act[((size_t)t * kk + j) * II + i_phys] = (__bf16)((u + 1.f) * glu * wv);
        }
      }
    }
  }
}

// ---------------- down MFMA GEMM ----------------
// M=64 slots, N=128 h, BK=64, 256 thr, waves 2x2, wave tile 32x64
__global__ __launch_bounds__(256, 2) void gemm_down(
    const __bf16* __restrict__ act,
    const int* __restrict__ dblk, const int* __restrict__ dscl,
    const int* __restrict__ lists, const int* __restrict__ counts,
    const int* __restrict__ dk, const int* __restrict__ tab,
    float* __restrict__ partial, int T)
{
  int te = tab[blockIdx.x];
  if (te < 0) return;
  int e = te >> 16, mtile = te & 0xFFFF;
  int cnt = counts[e];
  int n_valid = cnt - mtile * 64;
  if (n_valid <= 0) return;
  if (n_valid > 64) n_valid = 64;
  int kk = *dk; if (kk > KMAX) kk = KMAX; if (kk < 1) kk = 1;

  __shared__ int s_tok[64];
  __shared__ char Abuf[2][8192];   // 64 rows x 8 chunks
  __shared__ char Bbuf[2][16384];  // transposed: [chunk][h 0..127]

  int tid = threadIdx.x;
  if (tid < 64) {
    int idx = mtile * 64 + tid;
    s_tok[tid] = lists[e * T + (idx < cnt ? idx : mtile * 64)];
  }
  __syncthreads();

  int lane = tid & 63, w = tid >> 6;
  int r15 = lane & 15, sw = lane & 7;
  int wr = w >> 1, wc = w & 1;

  int cA = (lane & 7) ^ (lane >> 3);
  size_t aOff[2];
  #pragma unroll
  for (int q = 0; q < 2; ++q) {
    int row = w * 16 + q * 8 + (lane >> 3);
    int entry = s_tok[row];
    size_t slot = (size_t)(entry >> 3) * kk + (entry & 7);
    aOff[q] = slot * (II * 2) + (size_t)cA * 16;
  }

  int rB = tid >> 1, c4 = (tid & 1) * 4;
  int hbase = blockIdx.y * 128;
  int h_row = hbase + rB;
  const int4* bp = (const int4*)(dblk + ((size_t)e * HH + h_row) * (II / 2));
  const int* sp = dscl + ((size_t)e * HH + h_row) * (II / 32);

  f32x4 acc[2][4];
  #pragma unroll
  for (int a = 0; a < 2; ++a)
    #pragma unroll
    for (int b = 0; b < 4; ++b) acc[a][b] = (f32x4)0.f;

  #pragma unroll
  for (int q = 0; q < 2; ++q)
    gll16((const char*)act + aOff[q], Abuf[0] + w * 2048 + q * 1024);
  {
    int4 rw[4];
    #pragma unroll
    for (int j = 0; j < 4; ++j) rw[j] = bp[c4 + j];
    unsigned addk = make_addk(sp[tid & 1]);
    #pragma unroll
    for (int j = 0; j < 4; ++j)
      *(int4*)(Bbuf[0] + (c4 + j) * 2048 + rB * 16) = decode_chunk(rw[j], addk);
  }
  __syncthreads();

  constexpr int NK = II / 64;  // 16
  for (int kt = 0; kt < NK; ++kt) {
    char* An = Abuf[(kt + 1) & 1];
    char* Bn = Bbuf[(kt + 1) & 1];
    const char* Ac = Abuf[kt & 1];
    const char* Bc = Bbuf[kt & 1];
    int4 rw[4]; unsigned addk = 0;
    if (kt < NK - 1) {
      #pragma unroll
      for (int q = 0; q < 2; ++q)
        gll16((const char*)act + aOff[q] + (kt + 1) * 128, An + w * 2048 + q * 1024);
      #pragma unroll
      for (int j = 0; j < 4; ++j) rw[j] = bp[(kt + 1) * 8 + c4 + j];
      addk = make_addk(sp[(kt + 1) * 2 + (tid & 1)]);
    }
    #pragma unroll
    for (int kq = 0; kq < 2; ++kq) {
      int kc = kq * 4 + (lane >> 4);
      bf16x8 bf[4];
      #pragma unroll
      for (int fn = 0; fn < 4; ++fn)
        bf[fn] = *(const bf16x8*)(Bc + kc * 2048 + (wc * 64 + fn * 16 + r15) * 16);
      #pragma unroll
      for (int fm = 0; fm < 2; ++fm) {
        int m = wr * 32 + fm * 16 + r15;
        bf16x8 af = *(const bf16x8*)(Ac + m * 128 + ((kc ^ sw) * 16));
        #pragma unroll
        for (int fn = 0; fn < 4; ++fn)
          acc[fm][fn] = __builtin_amdgcn_mfma_f32_16x16x32_bf16(af, bf[fn], acc[fm][fn], 0, 0, 0);
      }
    }
    if (kt < NK - 1) {
      #pragma unroll
      for (int j = 0; j < 4; ++j)
        *(int4*)(Bn + (c4 + j) * 2048 + rB * 16) = decode_chunk(rw[j], addk);
    }
    __syncthreads();
  }

  #pragma unroll
  for (int fm = 0; fm < 2; ++fm) {
    #pragma unroll
    for (int rg = 0; rg < 4; ++rg) {
      int mloc = wr * 32 + fm * 16 + (lane >> 4) * 4 + rg;
      if (mloc < n_valid) {
        int entry = s_tok[mloc];
        int t = entry >> 3, j = entry & 7;
        size_t slot = (size_t)t * kk + j;
        #pragma unroll
        for (int fn = 0; fn < 4; ++fn) {
          int h = hbase + wc * 64 + fn * 16 + r15;
          partial[slot * HH + h] = acc[fm][fn][rg];
        }
      }
    }
  }
}

// ---------------- combine ----------------
__global__ void combine_kernel(const float* __restrict__ partial, const float* __restrict__ route,
                               const float* __restrict__ dbias, const int* __restrict__ dk,
                               float* __restrict__ out, int E) {
  int t = blockIdx.y;
  int h = blockIdx.x * 256 + threadIdx.x;
  int kk = *dk; if (kk > KMAX) kk = KMAX; if (kk < 1) kk = 1;
  float s = 0.f;
  for (int j = 0; j < kk; ++j) s += partial[((size_t)t * kk + j) * HH + h];
  for (int e = 0; e < E; ++e) s += route[t * E + e] * dbias[(size_t)e * HH + h];
  out[(size_t)t * HH + h] = s;
}

extern "C" void kernel_launch(void* const* d_in, const int* in_sizes, int n_in,
                              void* d_out, int out_size, void* d_ws, size_t ws_size,
                              hipStream_t stream) {
  const float* hs    = (const float*)d_in[0];
  const float* rl    = (const float*)d_in[1];
  const int*   gblk  = (const int*)d_in[2];
  const int*   gscl  = (const int*)d_in[3];
  const float* gbias = (const float*)d_in[4];
  const int*   ublk  = (const int*)d_in[5];
  const int*   uscl  = (const int*)d_in[6];
  const float* ubias = (const float*)d_in[7];
  const int*   dblk  = (const int*)d_in[8];
  const int*   dscl  = (const int*)d_in[9];
  const float* dbias = (const float*)d_in[10];
  const int*   dk    = (const int*)d_in[11];

  long s0 = in_sizes[0], s1 = in_sizes[1], s2 = in_sizes[2], s4 = in_sizes[4];
  int H = (int)(2 * s2 / s4);       // = 1024
  int T = (int)(s0 / H);            // = 1024
  int E = (int)(s1 / T);            // = 8

  char* w = (char*)d_ws;
  auto alloc = [&](size_t bytes) { char* p = w; w += (bytes + 255) & ~size_t(255); return p; };
  float*  route   = (float*)alloc(sizeof(float) * (size_t)T * E);
  int*    tidx    = (int*)  alloc(sizeof(int)   * (size_t)T * KMAX);
  float*  twp     = (float*)alloc(sizeof(float) * (size_t)T * KMAX);
  int*    counts  = (int*)  alloc(sizeof(int)   * (size_t)E);
  int*    lists   = (int*)  alloc(sizeof(int)   * (size_t)E * T);
  int*    tabGU   = (int*)  alloc(sizeof(int)   * GU_TILES);
  int*    tabDN   = (int*)  alloc(sizeof(int)   * DN_TILES);
  __bf16* hsb     = (__bf16*)alloc(sizeof(__bf16) * (size_t)T * HH);
  __bf16* act     = (__bf16*)alloc(sizeof(__bf16) * (size_t)T * KMAX * II);
  float*  partial = (float*)alloc(sizeof(float) * (size_t)T * KMAX * HH);

  routing_kernel<<<dim3((T + 255) / 256), 256, 0, stream>>>(rl, dk, T, E, route, tidx, twp);
  build_lists<<<dim3(E), 64, 0, stream>>>(tidx, dk, T, lists, counts);
  build_tiles<<<dim3(1), 64, 0, stream>>>(counts, E, tabGU, tabDN);
  convert_hs<<<dim3((T * HH / 8 + 255) / 256), 256, 0, stream>>>(hs, hsb, T * HH / 8);
  gemm_gate_up<<<dim3(GU_TILES, II * 2 / 128), 256, 0, stream>>>(
      hsb, gblk, gscl, gbias, ublk, uscl, ubias, lists, counts, twp, dk, tabGU, act, T);
  gemm_down<<<dim3(DN_TILES, HH / 128), 256, 0, stream>>>(
      act, dblk, dscl, lists, counts, dk, tabDN, partial, T);
  combine_kernel<<<dim3(HH / 256, T), 256, 0, stream>>>(partial, route, dbias, dk, (float*)d_out, E);
}